// Round 1
// baseline (1069.181 us; speedup 1.0000x reference)
//
#include <hip/hip_runtime.h>

#define N_NODES 65536
#define N_EDGES 1048576
#define DIM 64

// ---- order-preserving float <-> uint encoding for atomicMax on floats ----
__device__ __forceinline__ unsigned enc_f(float f) {
    unsigned u = __float_as_uint(f);
    return (u & 0x80000000u) ? ~u : (u | 0x80000000u);
}
__device__ __forceinline__ float dec_f(unsigned e) {
    return (e & 0x80000000u) ? __uint_as_float(e ^ 0x80000000u)
                             : __uint_as_float(~e);
}

__device__ __forceinline__ float lrelu(float x) {
    return x >= 0.f ? x : 0.01f * x;
}

// One wave (64 lanes) per node: s[n]=feats[n]·a_src, t[n]=feats[n]·a_dst.
// Also (re)initializes m and denom for this hop.
__global__ __launch_bounds__(256) void node_prep(
    const float* __restrict__ feats, const float* __restrict__ attn_w,
    float* __restrict__ s, float* __restrict__ t,
    unsigned* __restrict__ m, float* __restrict__ denom) {
    int node = blockIdx.x * 4 + (threadIdx.x >> 6);
    int lane = threadIdx.x & 63;
    float f = feats[node * DIM + lane];
    float sp = f * attn_w[lane];
    float tp = f * attn_w[DIM + lane];
    #pragma unroll
    for (int off = 32; off; off >>= 1) {
        sp += __shfl_xor(sp, off);
        tp += __shfl_xor(tp, off);
    }
    if (lane == 0) {
        s[node] = sp;
        t[node] = tp;
        m[node] = 0x007FFFFFu;  // enc(-inf)
        denom[node] = 0.f;
    }
}

// Thread per edge: segment max of e into m[dst].
__global__ __launch_bounds__(256) void edge_max(
    const int* __restrict__ src, const int* __restrict__ dst,
    const float* __restrict__ s, const float* __restrict__ t,
    const float* __restrict__ attn_b, unsigned* __restrict__ m) {
    int e = blockIdx.x * blockDim.x + threadIdx.x;
    if (e >= N_EDGES) return;
    int si = src[e], di = dst[e];
    float ev = lrelu(s[si] + t[di] + attn_b[0]);
    atomicMax(&m[di], enc_f(ev));
}

// Thread per edge: denom[dst] += exp(e - m[dst]).
__global__ __launch_bounds__(256) void edge_sum(
    const int* __restrict__ src, const int* __restrict__ dst,
    const float* __restrict__ s, const float* __restrict__ t,
    const float* __restrict__ attn_b, const unsigned* __restrict__ m,
    float* __restrict__ denom) {
    int e = blockIdx.x * blockDim.x + threadIdx.x;
    if (e >= N_EDGES) return;
    int si = src[e], di = dst[e];
    float ev = lrelu(s[si] + t[di] + attn_b[0]);
    float ex = expf(ev - dec_f(m[di]));
    atomicAdd(&denom[di], ex);
}

// One wave per edge, lane = feature dim:
// feats_out[dst][lane] += feats_in[src][lane] * w,  w = exp(e-m)/denom.
__global__ __launch_bounds__(256) void edge_agg(
    const int* __restrict__ src, const int* __restrict__ dst,
    const float* __restrict__ s, const float* __restrict__ t,
    const float* __restrict__ attn_b, const unsigned* __restrict__ m,
    const float* __restrict__ denom, const float* __restrict__ feats_in,
    float* __restrict__ feats_out) {
    int e = blockIdx.x * 4 + (threadIdx.x >> 6);
    int lane = threadIdx.x & 63;
    int si = src[e], di = dst[e];
    float ev = lrelu(s[si] + t[di] + attn_b[0]);
    float w = expf(ev - dec_f(m[di])) / denom[di];
    float val = feats_in[si * DIM + lane] * w;
    atomicAdd(&feats_out[di * DIM + lane], val);
}

// out = temp[0] * features   (float4 over N*D)
__global__ __launch_bounds__(256) void out_init(
    const float* __restrict__ feats, const float* __restrict__ temp,
    float* __restrict__ out) {
    int i = blockIdx.x * blockDim.x + threadIdx.x;
    float4 f = ((const float4*)feats)[i];
    float tk = temp[0];
    float4 o;
    o.x = tk * f.x; o.y = tk * f.y; o.z = tk * f.z; o.w = tk * f.w;
    ((float4*)out)[i] = o;
}

// out += temp[k] * feats_new   (float4 over N*D)
__global__ __launch_bounds__(256) void out_accum(
    const float* __restrict__ feats_new, const float* __restrict__ temp,
    int k, float* __restrict__ out) {
    int i = blockIdx.x * blockDim.x + threadIdx.x;
    float4 f = ((const float4*)feats_new)[i];
    float4 o = ((float4*)out)[i];
    float tk = temp[k];
    o.x += tk * f.x; o.y += tk * f.y; o.z += tk * f.z; o.w += tk * f.w;
    ((float4*)out)[i] = o;
}

extern "C" void kernel_launch(void* const* d_in, const int* in_sizes, int n_in,
                              void* d_out, int out_size, void* d_ws, size_t ws_size,
                              hipStream_t stream) {
    const float* features = (const float*)d_in[0];
    const int* src = (const int*)d_in[1];
    const int* dst = (const int*)d_in[2];
    const float* attn_w = (const float*)d_in[3];
    const float* attn_b = (const float*)d_in[4];
    const float* temp = (const float*)d_in[5];
    float* out = (float*)d_out;

    // workspace layout
    float* s = (float*)d_ws;               // N
    float* t = s + N_NODES;                // N
    unsigned* m = (unsigned*)(t + N_NODES); // N
    float* denom = (float*)(m + N_NODES);  // N
    float* bufA = denom + N_NODES;         // N*DIM
    float* bufB = bufA + N_NODES * DIM;    // N*DIM

    const int EDGE_BLOCKS = N_EDGES / 256;       // 4096
    const int NODE_BLOCKS = N_NODES / 4;         // 16384 (4 nodes/block)
    const int AGG_BLOCKS = N_EDGES / 4;          // 262144 (4 edges/block)
    const int VEC_BLOCKS = (N_NODES * DIM / 4) / 256;  // 4096

    out_init<<<VEC_BLOCKS, 256, 0, stream>>>(features, temp, out);

    const float* feats_in = features;
    for (int k = 0; k < 3; ++k) {
        float* feats_out = (k & 1) ? bufB : bufA;

        node_prep<<<NODE_BLOCKS, 256, 0, stream>>>(feats_in, attn_w, s, t, m, denom);
        edge_max<<<EDGE_BLOCKS, 256, 0, stream>>>(src, dst, s, t, attn_b, m);
        edge_sum<<<EDGE_BLOCKS, 256, 0, stream>>>(src, dst, s, t, attn_b, m, denom);
        hipMemsetAsync(feats_out, 0, (size_t)N_NODES * DIM * sizeof(float), stream);
        edge_agg<<<AGG_BLOCKS, 256, 0, stream>>>(src, dst, s, t, attn_b, m, denom,
                                                 feats_in, feats_out);
        out_accum<<<VEC_BLOCKS, 256, 0, stream>>>(feats_out, temp, k + 1, out);

        feats_in = feats_out;
    }
}

// Round 2
// 391.894 us; speedup vs baseline: 2.7282x; 2.7282x over previous
//
#include <hip/hip_runtime.h>

#define N_NODES 65536
#define N_EDGES 1048576
#define DIM 64

__device__ __forceinline__ float lrelu(float x) { return x >= 0.f ? x : 0.01f * x; }

// ---- s[n] = feats[n] . a_src  (one wave per node, lane = dim) ----
__global__ __launch_bounds__(256) void node_s(
    const float* __restrict__ feats, const float* __restrict__ attn_w,
    float* __restrict__ s) {
    int node = blockIdx.x * 4 + (threadIdx.x >> 6);
    int lane = threadIdx.x & 63;
    float sp = feats[node * DIM + lane] * attn_w[lane];
    #pragma unroll
    for (int off = 32; off; off >>= 1) sp += __shfl_xor(sp, off);
    if (lane == 0) s[node] = sp;
}

// ---- CSR build: histogram of dst ----
__global__ __launch_bounds__(256) void hist(
    const int* __restrict__ dst, unsigned* __restrict__ counts) {
    int e = blockIdx.x * 256 + threadIdx.x;
    atomicAdd(&counts[dst[e]], 1u);
}

// ---- exclusive scan, level 1: 256 blocks x 256 elems ----
__global__ __launch_bounds__(256) void scan1(
    const unsigned* __restrict__ counts, unsigned* __restrict__ row_start,
    unsigned* __restrict__ blockSums) {
    __shared__ unsigned sd[256];
    int tid = threadIdx.x;
    int i = blockIdx.x * 256 + tid;
    unsigned v = counts[i];
    sd[tid] = v;
    __syncthreads();
    #pragma unroll
    for (int off = 1; off < 256; off <<= 1) {
        unsigned x = (tid >= off) ? sd[tid - off] : 0u;
        __syncthreads();
        sd[tid] += x;
        __syncthreads();
    }
    row_start[i] = sd[tid] - v;           // exclusive
    if (tid == 255) blockSums[blockIdx.x] = sd[255];
}

// ---- exclusive scan, level 2: single block over 256 block sums ----
__global__ __launch_bounds__(256) void scan2(unsigned* __restrict__ blockSums) {
    __shared__ unsigned sd[256];
    int tid = threadIdx.x;
    unsigned v = blockSums[tid];
    sd[tid] = v;
    __syncthreads();
    #pragma unroll
    for (int off = 1; off < 256; off <<= 1) {
        unsigned x = (tid >= off) ? sd[tid - off] : 0u;
        __syncthreads();
        sd[tid] += x;
        __syncthreads();
    }
    blockSums[tid] = sd[tid] - v;
}

// ---- add block offsets; append total sentinel ----
__global__ __launch_bounds__(256) void scan3(
    unsigned* __restrict__ row_start, const unsigned* __restrict__ blockSums) {
    int i = blockIdx.x * 256 + threadIdx.x;
    row_start[i] += blockSums[blockIdx.x];
    if (i == 0) row_start[N_NODES] = N_EDGES;
}

// ---- scatter src ids into CSR order ----
__global__ __launch_bounds__(256) void scatter(
    const int* __restrict__ src, const int* __restrict__ dst,
    const unsigned* __restrict__ row_start, unsigned* __restrict__ cursor,
    int* __restrict__ csr_src) {
    int e = blockIdx.x * 256 + threadIdx.x;
    int d = dst[e];
    unsigned pos = row_start[d] + atomicAdd(&cursor[d], 1u);
    csr_src[pos] = src[e];
}

// ---- main aggregation: one wave per dst node, lane = feature dim ----
// feats_out[n] = (sum_j exp(e_j - m) * feats_in[src_j]) / (sum_j exp(e_j - m))
// out[n] (+)= temp[k+1] * feats_out[n]   (k==0 also initializes with temp[0]*feats)
__global__ __launch_bounds__(256) void node_agg(
    const float* __restrict__ feats_in, const float* __restrict__ s,
    const unsigned* __restrict__ row_start, const int* __restrict__ csr_src,
    const float* __restrict__ attn_w, const float* __restrict__ attn_b,
    const float* __restrict__ temp, int k,
    float* __restrict__ feats_out, float* __restrict__ out) {
    int node = blockIdx.x * 4 + (threadIdx.x >> 6);
    int lane = threadIdx.x & 63;

    float fown = feats_in[node * DIM + lane];
    float tp = fown * attn_w[DIM + lane];
    #pragma unroll
    for (int off = 32; off; off >>= 1) tp += __shfl_xor(tp, off);
    float b = attn_b[0];

    unsigned beg = row_start[node], end = row_start[node + 1];

    // pass 1: segment max (lanes strided over edges)
    float mx = -3.402823e38f;
    for (unsigned j = beg + lane; j < end; j += 64)
        mx = fmaxf(mx, lrelu(s[csr_src[j]] + tp + b));
    #pragma unroll
    for (int off = 32; off; off >>= 1) mx = fmaxf(mx, __shfl_xor(mx, off));

    // pass 2: denom partials + aggregation, chunked 64 edges at a time
    float dn = 0.f, acc = 0.f;
    for (unsigned base = beg; base < end; base += 64) {
        unsigned j = base + lane;
        bool valid = j < end;
        int sj_l = valid ? csr_src[j] : 0;
        float ev_l = valid ? expf(lrelu(s[sj_l] + tp + b) - mx) : 0.f;
        dn += ev_l;
        int cnt = (int)min(64u, end - base);
        for (int i = 0; i < cnt; ++i) {
            int sj = __shfl(sj_l, i);
            float w = __shfl(ev_l, i);
            acc += w * feats_in[sj * DIM + lane];
        }
    }
    #pragma unroll
    for (int off = 32; off; off >>= 1) dn += __shfl_xor(dn, off);
    acc = (end > beg) ? (acc / dn) : 0.f;

    feats_out[node * DIM + lane] = acc;
    float o = (k == 0) ? temp[0] * fown : out[node * DIM + lane];
    out[node * DIM + lane] = o + temp[k + 1] * acc;
}

extern "C" void kernel_launch(void* const* d_in, const int* in_sizes, int n_in,
                              void* d_out, int out_size, void* d_ws, size_t ws_size,
                              hipStream_t stream) {
    const float* features = (const float*)d_in[0];
    const int* src = (const int*)d_in[1];
    const int* dst = (const int*)d_in[2];
    const float* attn_w = (const float*)d_in[3];
    const float* attn_b = (const float*)d_in[4];
    const float* temp = (const float*)d_in[5];
    float* out = (float*)d_out;

    // workspace layout (floats/uints, all 4B)
    float* s = (float*)d_ws;                        // N
    unsigned* counts = (unsigned*)(s + N_NODES);    // N (also reused as cursor)
    unsigned* row_start = counts + N_NODES;         // N + 64 (sentinel + pad)
    unsigned* blockSums = row_start + N_NODES + 64; // 256
    int* csr_src = (int*)(blockSums + 256);         // N_EDGES
    float* bufA = (float*)(csr_src + N_EDGES);      // N*DIM
    float* bufB = bufA + (size_t)N_NODES * DIM;     // N*DIM

    const int EDGE_BLOCKS = N_EDGES / 256;   // 4096
    const int NODE_BLOCKS = N_NODES / 4;     // 16384 (4 waves/block, 1 node/wave)

    // ---- build CSR (by dst) once; reused by all 3 hops ----
    hipMemsetAsync(counts, 0, N_NODES * sizeof(unsigned), stream);
    hist<<<EDGE_BLOCKS, 256, 0, stream>>>(dst, counts);
    scan1<<<N_NODES / 256, 256, 0, stream>>>(counts, row_start, blockSums);
    scan2<<<1, 256, 0, stream>>>(blockSums);
    scan3<<<N_NODES / 256, 256, 0, stream>>>(row_start, blockSums);
    hipMemsetAsync(counts, 0, N_NODES * sizeof(unsigned), stream);
    scatter<<<EDGE_BLOCKS, 256, 0, stream>>>(src, dst, row_start, counts, csr_src);

    // ---- 3 hops ----
    const float* feats_in = features;
    for (int k = 0; k < 3; ++k) {
        float* feats_out = (k & 1) ? bufB : bufA;
        node_s<<<NODE_BLOCKS, 256, 0, stream>>>(feats_in, attn_w, s);
        node_agg<<<NODE_BLOCKS, 256, 0, stream>>>(feats_in, s, row_start, csr_src,
                                                  attn_w, attn_b, temp, k,
                                                  feats_out, out);
        feats_in = feats_out;
    }
}

// Round 4
// 272.453 us; speedup vs baseline: 3.9243x; 1.4384x over previous
//
#include <hip/hip_runtime.h>

#define N_NODES 65536
#define N_EDGES 1048576
#define DIM 64

__device__ __forceinline__ float lrelu(float x) { return x >= 0.f ? x : 0.01f * x; }

// ---- s[n] = feats[n] . a_src  (initial hop only; later hops fused) ----
__global__ __launch_bounds__(256) void node_s(
    const float* __restrict__ feats, const float* __restrict__ attn_w,
    float* __restrict__ s) {
    int node = blockIdx.x * 4 + (threadIdx.x >> 6);
    int lane = threadIdx.x & 63;
    float sp = feats[node * DIM + lane] * attn_w[lane];
    #pragma unroll
    for (int off = 32; off; off >>= 1) sp += __shfl_xor(sp, off);
    if (lane == 0) s[node] = sp;
}

// ---- CSR build: histogram of dst ----
__global__ __launch_bounds__(256) void hist(
    const int* __restrict__ dst, unsigned* __restrict__ counts) {
    int e = blockIdx.x * 256 + threadIdx.x;
    atomicAdd(&counts[dst[e]], 1u);
}

__global__ __launch_bounds__(256) void scan1(
    const unsigned* __restrict__ counts, unsigned* __restrict__ row_start,
    unsigned* __restrict__ blockSums) {
    __shared__ unsigned sd[256];
    int tid = threadIdx.x;
    int i = blockIdx.x * 256 + tid;
    unsigned v = counts[i];
    sd[tid] = v;
    __syncthreads();
    #pragma unroll
    for (int off = 1; off < 256; off <<= 1) {
        unsigned x = (tid >= off) ? sd[tid - off] : 0u;
        __syncthreads();
        sd[tid] += x;
        __syncthreads();
    }
    row_start[i] = sd[tid] - v;  // exclusive
    if (tid == 255) blockSums[blockIdx.x] = sd[255];
}

__global__ __launch_bounds__(256) void scan2(unsigned* __restrict__ blockSums) {
    __shared__ unsigned sd[256];
    int tid = threadIdx.x;
    unsigned v = blockSums[tid];
    sd[tid] = v;
    __syncthreads();
    #pragma unroll
    for (int off = 1; off < 256; off <<= 1) {
        unsigned x = (tid >= off) ? sd[tid - off] : 0u;
        __syncthreads();
        sd[tid] += x;
        __syncthreads();
    }
    blockSums[tid] = sd[tid] - v;
}

__global__ __launch_bounds__(256) void scan3(
    unsigned* __restrict__ row_start, const unsigned* __restrict__ blockSums) {
    int i = blockIdx.x * 256 + threadIdx.x;
    row_start[i] += blockSums[blockIdx.x];
    if (i == 0) row_start[N_NODES] = N_EDGES;
}

__global__ __launch_bounds__(256) void scatter(
    const int* __restrict__ src, const int* __restrict__ dst,
    const unsigned* __restrict__ row_start, unsigned* __restrict__ cursor,
    int* __restrict__ csr_src) {
    int e = blockIdx.x * 256 + threadIdx.x;
    int d = dst[e];
    unsigned pos = row_start[d] + atomicAdd(&cursor[d], 1u);
    csr_src[pos] = src[e];
}

// ---- main aggregation: one wave per dst node ----
// Gather: 4 groups of 16 lanes; per UNIFORM iteration (t8 += 16) group g pulls
// edges t8+g, t8+g+4, t8+g+8, t8+g+12 as float4 rows (4 gathers in flight).
// All __shfl are executed by all 64 lanes (no divergence); invalid edge slots
// carry ev_l=0 / sj_l=0 so they self-gate.
// Epilogue fuses: feats_out write, out accumulation, s_next = feats_out.a_src.
__global__ __launch_bounds__(256) void node_agg(
    const float* __restrict__ feats_in, const float* __restrict__ s_in,
    const unsigned* __restrict__ row_start, const int* __restrict__ csr_src,
    const float* __restrict__ attn_w, const float* __restrict__ attn_b,
    const float* __restrict__ temp, int k, int last,
    float* __restrict__ feats_out, float* __restrict__ s_next,
    float* __restrict__ out) {
    int node = blockIdx.x * 4 + (threadIdx.x >> 6);
    int lane = threadIdx.x & 63;
    int g = lane >> 4, l16 = lane & 15;

    float fown = feats_in[node * DIM + lane];
    float tp = fown * attn_w[DIM + lane];
    #pragma unroll
    for (int off = 32; off; off >>= 1) tp += __shfl_xor(tp, off);
    float b = attn_b[0];

    unsigned beg = row_start[node];
    int deg = (int)(row_start[node + 1] - beg);

    // pass 1: segment max (lanes strided over edges)
    float mx = -3.402823e38f;
    for (int j = lane; j < deg; j += 64)
        mx = fmaxf(mx, lrelu(s_in[csr_src[beg + j]] + tp + b));
    #pragma unroll
    for (int off = 32; off; off >>= 1) mx = fmaxf(mx, __shfl_xor(mx, off));

    // pass 2: denom + weighted row gather, 64 edges per chunk
    float dn = 0.f;
    float4 acc = make_float4(0.f, 0.f, 0.f, 0.f);
    const float4* feats4 = (const float4*)feats_in;
    for (int base = 0; base < deg; base += 64) {
        int j = base + lane;
        bool valid = j < deg;
        int sj_l = valid ? csr_src[beg + j] : 0;
        float ev_l = valid ? expf(lrelu(s_in[sj_l] + tp + b) - mx) : 0.f;
        dn += ev_l;
        int cnt = min(64, deg - base);
        // uniform trip count: cnt is identical across the wave
        for (int t8 = 0; t8 < cnt; t8 += 16) {
            int i0 = t8 + g;           // <= 51
            int i1 = i0 + 4;           // <= 55
            int i2 = i0 + 8;           // <= 59
            int i3 = i0 + 12;          // <= 63
            int   sj0 = __shfl(sj_l, i0);
            float w0  = __shfl(ev_l, i0);
            int   sj1 = __shfl(sj_l, i1);
            float w1  = __shfl(ev_l, i1);
            int   sj2 = __shfl(sj_l, i2);
            float w2  = __shfl(ev_l, i2);
            int   sj3 = __shfl(sj_l, i3);
            float w3  = __shfl(ev_l, i3);
            float4 f0 = feats4[sj0 * 16 + l16];
            float4 f1 = feats4[sj1 * 16 + l16];
            float4 f2 = feats4[sj2 * 16 + l16];
            float4 f3 = feats4[sj3 * 16 + l16];
            acc.x += w0 * f0.x + w1 * f1.x + w2 * f2.x + w3 * f3.x;
            acc.y += w0 * f0.y + w1 * f1.y + w2 * f2.y + w3 * f3.y;
            acc.z += w0 * f0.z + w1 * f1.z + w2 * f2.z + w3 * f3.z;
            acc.w += w0 * f0.w + w1 * f1.w + w2 * f2.w + w3 * f3.w;
        }
    }
    // fold the 4 edge-groups together (lanes with equal l16)
    #pragma unroll
    for (int off = 32; off >= 16; off >>= 1) {
        acc.x += __shfl_xor(acc.x, off);
        acc.y += __shfl_xor(acc.y, off);
        acc.z += __shfl_xor(acc.z, off);
        acc.w += __shfl_xor(acc.w, off);
    }
    #pragma unroll
    for (int off = 32; off; off >>= 1) dn += __shfl_xor(dn, off);
    float inv = (deg > 0) ? 1.f / dn : 0.f;

    // transpose float4-chunk layout -> scalar lane layout (lane d = dim d)
    int srcl = lane >> 2;
    float vx = __shfl(acc.x, srcl);
    float vy = __shfl(acc.y, srcl);
    float vz = __shfl(acc.z, srcl);
    float vw = __shfl(acc.w, srcl);
    int c = lane & 3;
    float a = (c == 0) ? vx : (c == 1) ? vy : (c == 2) ? vz : vw;
    a *= inv;

    if (!last) feats_out[node * DIM + lane] = a;
    float o = (k == 0) ? temp[0] * fown : out[node * DIM + lane];
    out[node * DIM + lane] = o + temp[k + 1] * a;

    if (!last) {  // fused s for next hop
        float sp = a * attn_w[lane];
        #pragma unroll
        for (int off = 32; off; off >>= 1) sp += __shfl_xor(sp, off);
        if (lane == 0) s_next[node] = sp;
    }
}

extern "C" void kernel_launch(void* const* d_in, const int* in_sizes, int n_in,
                              void* d_out, int out_size, void* d_ws, size_t ws_size,
                              hipStream_t stream) {
    const float* features = (const float*)d_in[0];
    const int* src = (const int*)d_in[1];
    const int* dst = (const int*)d_in[2];
    const float* attn_w = (const float*)d_in[3];
    const float* attn_b = (const float*)d_in[4];
    const float* temp = (const float*)d_in[5];
    float* out = (float*)d_out;

    // workspace layout (all 4B elems; float4 bufs stay 16B-aligned)
    float* s0 = (float*)d_ws;                        // N
    float* s1 = s0 + N_NODES;                        // N
    unsigned* counts = (unsigned*)(s1 + N_NODES);    // N (reused as cursor)
    unsigned* row_start = counts + N_NODES;          // N + 64 (sentinel + pad)
    unsigned* blockSums = row_start + N_NODES + 64;  // 256
    int* csr_src = (int*)(blockSums + 256);          // N_EDGES
    float* bufA = (float*)(csr_src + N_EDGES);       // N*DIM
    float* bufB = bufA + (size_t)N_NODES * DIM;      // N*DIM

    const int EDGE_BLOCKS = N_EDGES / 256;   // 4096
    const int NODE_BLOCKS = N_NODES / 4;     // 16384

    // ---- build CSR (by dst) once; reused by all 3 hops ----
    hipMemsetAsync(counts, 0, N_NODES * sizeof(unsigned), stream);
    hist<<<EDGE_BLOCKS, 256, 0, stream>>>(dst, counts);
    scan1<<<N_NODES / 256, 256, 0, stream>>>(counts, row_start, blockSums);
    scan2<<<1, 256, 0, stream>>>(blockSums);
    scan3<<<N_NODES / 256, 256, 0, stream>>>(row_start, blockSums);
    hipMemsetAsync(counts, 0, N_NODES * sizeof(unsigned), stream);
    scatter<<<EDGE_BLOCKS, 256, 0, stream>>>(src, dst, row_start, counts, csr_src);

    node_s<<<NODE_BLOCKS, 256, 0, stream>>>(features, attn_w, s0);

    // ---- 3 hops ----
    const float* feats_in = features;
    for (int k = 0; k < 3; ++k) {
        int last = (k == 2);
        float* feats_out = (k & 1) ? bufB : bufA;
        float* s_in = (k & 1) ? s1 : s0;
        float* s_nx = (k & 1) ? s0 : s1;
        node_agg<<<NODE_BLOCKS, 256, 0, stream>>>(feats_in, s_in, row_start, csr_src,
                                                  attn_w, attn_b, temp, k, last,
                                                  feats_out, s_nx, out);
        feats_in = feats_out;
    }
}

// Round 5
// 243.436 us; speedup vs baseline: 4.3920x; 1.1192x over previous
//
#include <hip/hip_runtime.h>

#define N_NODES 65536
#define N_EDGES 1048576
#define DIM 64
#define NXCD 8
#define PART_BLOCKS 2048   // 256 blocks per XCD group
#define NODES_PER_GRP (N_NODES / NXCD)   // 8192

__device__ __forceinline__ float lrelu(float x) { return x >= 0.f ? x : 0.01f * x; }

// ---- s[n] = feats[n] . a_src  (initial hop only; later hops fused) ----
__global__ __launch_bounds__(256) void node_s(
    const float* __restrict__ feats, const float* __restrict__ attn_w,
    float* __restrict__ s) {
    int node = blockIdx.x * 4 + (threadIdx.x >> 6);
    int lane = threadIdx.x & 63;
    float sp = feats[node * DIM + lane] * attn_w[lane];
    #pragma unroll
    for (int off = 32; off; off >>= 1) sp += __shfl_xor(sp, off);
    if (lane == 0) s[node] = sp;
}

// ---- XCD-partitioned histogram of dst ----
// group g (blockIdx & 7, XCD round-robin heuristic) handles dst range
// [g*8192, (g+1)*8192): atomics stay in one XCD's L2.
__global__ __launch_bounds__(256) void hist_part(
    const int* __restrict__ dst, unsigned* __restrict__ counts) {
    int grp = blockIdx.x & (NXCD - 1);
    int blkInGrp = blockIdx.x >> 3;
    int lo = grp * NODES_PER_GRP, hi = lo + NODES_PER_GRP;
    const int stride = (PART_BLOCKS / NXCD) * 256;  // 65536
    for (int e = blkInGrp * 256 + threadIdx.x; e < N_EDGES; e += stride) {
        int d = dst[e];
        if (d >= lo && d < hi) atomicAdd(&counts[d], 1u);
    }
}

// ---- exclusive scan, level 1 (also re-zeroes counts for cursor reuse) ----
__global__ __launch_bounds__(256) void scan1(
    unsigned* __restrict__ counts, unsigned* __restrict__ row_start,
    unsigned* __restrict__ blockSums) {
    __shared__ unsigned sd[256];
    int tid = threadIdx.x;
    int i = blockIdx.x * 256 + tid;
    unsigned v = counts[i];
    counts[i] = 0u;  // cursor for scatter
    sd[tid] = v;
    __syncthreads();
    #pragma unroll
    for (int off = 1; off < 256; off <<= 1) {
        unsigned x = (tid >= off) ? sd[tid - off] : 0u;
        __syncthreads();
        sd[tid] += x;
        __syncthreads();
    }
    row_start[i] = sd[tid] - v;  // exclusive
    if (tid == 255) blockSums[blockIdx.x] = sd[255];
}

__global__ __launch_bounds__(256) void scan2(unsigned* __restrict__ blockSums) {
    __shared__ unsigned sd[256];
    int tid = threadIdx.x;
    unsigned v = blockSums[tid];
    sd[tid] = v;
    __syncthreads();
    #pragma unroll
    for (int off = 1; off < 256; off <<= 1) {
        unsigned x = (tid >= off) ? sd[tid - off] : 0u;
        __syncthreads();
        sd[tid] += x;
        __syncthreads();
    }
    blockSums[tid] = sd[tid] - v;
}

__global__ __launch_bounds__(256) void scan3(
    unsigned* __restrict__ row_start, const unsigned* __restrict__ blockSums) {
    int i = blockIdx.x * 256 + threadIdx.x;
    row_start[i] += blockSums[blockIdx.x];
    if (i == 0) row_start[N_NODES] = N_EDGES;
}

// ---- XCD-partitioned scatter of src ids into CSR order ----
// Same group->dst-range mapping as hist_part: cursor atomics AND csr_src
// writes for a range stay in one XCD's L2 (writeback ~4MB instead of 74MB).
__global__ __launch_bounds__(256) void scatter_part(
    const int* __restrict__ src, const int* __restrict__ dst,
    const unsigned* __restrict__ row_start, unsigned* __restrict__ cursor,
    int* __restrict__ csr_src) {
    int grp = blockIdx.x & (NXCD - 1);
    int blkInGrp = blockIdx.x >> 3;
    int lo = grp * NODES_PER_GRP, hi = lo + NODES_PER_GRP;
    const int stride = (PART_BLOCKS / NXCD) * 256;
    for (int e = blkInGrp * 256 + threadIdx.x; e < N_EDGES; e += stride) {
        int d = dst[e];
        if (d >= lo && d < hi) {
            unsigned pos = row_start[d] + atomicAdd(&cursor[d], 1u);
            csr_src[pos] = src[e];
        }
    }
}

// ---- main aggregation: one wave per dst node, single pass (no max) ----
// Softmax without max-subtraction: |e| <= ~7 here, exp() is fp32-safe and
// the weight ratios are identical. Gather: 4 groups of 16 lanes; per uniform
// iteration group g pulls edges t8+g, +4, +8, +12 as float4 rows.
// Epilogue fuses: feats_out write, out accumulation, s_next = feats_out.a_src.
__global__ __launch_bounds__(256) void node_agg(
    const float* __restrict__ feats_in, const float* __restrict__ s_in,
    const unsigned* __restrict__ row_start, const int* __restrict__ csr_src,
    const float* __restrict__ attn_w, const float* __restrict__ attn_b,
    const float* __restrict__ temp, int k, int last,
    float* __restrict__ feats_out, float* __restrict__ s_next,
    float* __restrict__ out) {
    int node = blockIdx.x * 4 + (threadIdx.x >> 6);
    int lane = threadIdx.x & 63;
    int g = lane >> 4, l16 = lane & 15;

    float fown = feats_in[node * DIM + lane];
    float tp = fown * attn_w[DIM + lane];
    #pragma unroll
    for (int off = 32; off; off >>= 1) tp += __shfl_xor(tp, off);
    float b = attn_b[0];

    unsigned beg = row_start[node];
    int deg = (int)(row_start[node + 1] - beg);

    float dn = 0.f;
    float4 acc = make_float4(0.f, 0.f, 0.f, 0.f);
    const float4* feats4 = (const float4*)feats_in;
    for (int base = 0; base < deg; base += 64) {
        int j = base + lane;
        bool valid = j < deg;
        int sj_l = valid ? csr_src[beg + j] : 0;
        float ev_l = valid ? expf(lrelu(s_in[sj_l] + tp + b)) : 0.f;
        dn += ev_l;
        int cnt = min(64, deg - base);
        // uniform trip count across the wave; all shuffles convergent
        for (int t8 = 0; t8 < cnt; t8 += 16) {
            int i0 = t8 + g;
            int   sj0 = __shfl(sj_l, i0);
            float w0  = __shfl(ev_l, i0);
            int   sj1 = __shfl(sj_l, i0 + 4);
            float w1  = __shfl(ev_l, i0 + 4);
            int   sj2 = __shfl(sj_l, i0 + 8);
            float w2  = __shfl(ev_l, i0 + 8);
            int   sj3 = __shfl(sj_l, i0 + 12);
            float w3  = __shfl(ev_l, i0 + 12);
            float4 f0 = feats4[sj0 * 16 + l16];
            float4 f1 = feats4[sj1 * 16 + l16];
            float4 f2 = feats4[sj2 * 16 + l16];
            float4 f3 = feats4[sj3 * 16 + l16];
            acc.x += w0 * f0.x + w1 * f1.x + w2 * f2.x + w3 * f3.x;
            acc.y += w0 * f0.y + w1 * f1.y + w2 * f2.y + w3 * f3.y;
            acc.z += w0 * f0.z + w1 * f1.z + w2 * f2.z + w3 * f3.z;
            acc.w += w0 * f0.w + w1 * f1.w + w2 * f2.w + w3 * f3.w;
        }
    }
    // fold the 4 edge-groups together (lanes with equal l16)
    #pragma unroll
    for (int off = 32; off >= 16; off >>= 1) {
        acc.x += __shfl_xor(acc.x, off);
        acc.y += __shfl_xor(acc.y, off);
        acc.z += __shfl_xor(acc.z, off);
        acc.w += __shfl_xor(acc.w, off);
    }
    #pragma unroll
    for (int off = 32; off; off >>= 1) dn += __shfl_xor(dn, off);
    float inv = (deg > 0) ? 1.f / dn : 0.f;

    // transpose float4-chunk layout -> scalar lane layout (lane d = dim d)
    int srcl = lane >> 2;
    float vx = __shfl(acc.x, srcl);
    float vy = __shfl(acc.y, srcl);
    float vz = __shfl(acc.z, srcl);
    float vw = __shfl(acc.w, srcl);
    int c = lane & 3;
    float a = (c == 0) ? vx : (c == 1) ? vy : (c == 2) ? vz : vw;
    a *= inv;

    if (!last) feats_out[node * DIM + lane] = a;
    float o = (k == 0) ? temp[0] * fown : out[node * DIM + lane];
    out[node * DIM + lane] = o + temp[k + 1] * a;

    if (!last) {  // fused s for next hop
        float sp = a * attn_w[lane];
        #pragma unroll
        for (int off = 32; off; off >>= 1) sp += __shfl_xor(sp, off);
        if (lane == 0) s_next[node] = sp;
    }
}

extern "C" void kernel_launch(void* const* d_in, const int* in_sizes, int n_in,
                              void* d_out, int out_size, void* d_ws, size_t ws_size,
                              hipStream_t stream) {
    const float* features = (const float*)d_in[0];
    const int* src = (const int*)d_in[1];
    const int* dst = (const int*)d_in[2];
    const float* attn_w = (const float*)d_in[3];
    const float* attn_b = (const float*)d_in[4];
    const float* temp = (const float*)d_in[5];
    float* out = (float*)d_out;

    // workspace layout (all 4B elems; float4 bufs stay 16B-aligned)
    float* s0 = (float*)d_ws;                        // N
    float* s1 = s0 + N_NODES;                        // N
    unsigned* counts = (unsigned*)(s1 + N_NODES);    // N (reused as cursor)
    unsigned* row_start = counts + N_NODES;          // N + 64 (sentinel + pad)
    unsigned* blockSums = row_start + N_NODES + 64;  // 256
    int* csr_src = (int*)(blockSums + 256);          // N_EDGES
    float* bufA = (float*)(csr_src + N_EDGES);       // N*DIM
    float* bufB = bufA + (size_t)N_NODES * DIM;      // N*DIM

    const int NODE_BLOCKS = N_NODES / 4;     // 16384

    // ---- build CSR (by dst) once; reused by all 3 hops ----
    hipMemsetAsync(counts, 0, N_NODES * sizeof(unsigned), stream);
    hist_part<<<PART_BLOCKS, 256, 0, stream>>>(dst, counts);
    scan1<<<N_NODES / 256, 256, 0, stream>>>(counts, row_start, blockSums);
    scan2<<<1, 256, 0, stream>>>(blockSums);
    scan3<<<N_NODES / 256, 256, 0, stream>>>(row_start, blockSums);
    scatter_part<<<PART_BLOCKS, 256, 0, stream>>>(src, dst, row_start, counts, csr_src);

    node_s<<<NODE_BLOCKS, 256, 0, stream>>>(features, attn_w, s0);

    // ---- 3 hops ----
    const float* feats_in = features;
    for (int k = 0; k < 3; ++k) {
        int last = (k == 2);
        float* feats_out = (k & 1) ? bufB : bufA;
        float* s_in = (k & 1) ? s1 : s0;
        float* s_nx = (k & 1) ? s0 : s1;
        node_agg<<<NODE_BLOCKS, 256, 0, stream>>>(feats_in, s_in, row_start, csr_src,
                                                  attn_w, attn_b, temp, k, last,
                                                  feats_out, s_nx, out);
        feats_in = feats_out;
    }
}